// Round 12
// baseline (984.252 us; speedup 1.0000x reference)
//
#include <hip/hip_runtime.h>

#define TPB 256
#define RBITS 10               // bucket = node >> 10 (1024 nodes/bucket)
#define RSZ   1024
#define BMAX  512              // max buckets supported (N <= 512K)
#define CHUNK 4096             // edges per block in bucket passes
constexpr float EPSV = 1e-5f;

__device__ __forceinline__ float bf2f(unsigned short u) {
  return __uint_as_float((unsigned)u << 16);
}
__device__ __forceinline__ unsigned short f2bf(float f) {
  unsigned u = __float_as_uint(f);
  return (unsigned short)((u + 0x7fffu + ((u >> 16) & 1u)) >> 16);  // RNE
}

// =================== bucket-sorted CSR build ===================

__global__ void k_bcnt(const int* __restrict__ col, int* __restrict__ bcnt, int E, int B) {
  __shared__ int h[BMAX];
  const int tid = threadIdx.x;
  for (int i = tid; i < B; i += TPB) h[i] = 0;
  __syncthreads();
  const int e0 = blockIdx.x * CHUNK;
  for (int k = tid; k < CHUNK; k += TPB) {
    int i = e0 + k;
    if (i < E) atomicAdd(&h[col[i] >> RBITS], 1);
  }
  __syncthreads();
  for (int i = tid; i < B; i += TPB)
    if (h[i]) atomicAdd(&bcnt[i], h[i]);
}

__global__ void k_bscan(const int* __restrict__ bcnt, int* __restrict__ bbase,
                        int* __restrict__ bcur, int B, int E) {
  __shared__ int red[BMAX];
  const int tid = threadIdx.x;  // 512 threads
  int v = (tid < B) ? bcnt[tid] : 0;
  red[tid] = v;
  __syncthreads();
  for (int off = 1; off < BMAX; off <<= 1) {
    int u = (tid >= off) ? red[tid - off] : 0;
    __syncthreads();
    red[tid] += u;
    __syncthreads();
  }
  int excl = red[tid] - v;
  if (tid < B) { bbase[tid] = excl; bcur[tid] = excl; }
  if (tid == 0) bbase[B] = E;
}

__global__ void k_binfill(const int* __restrict__ row, const int* __restrict__ col,
                          const float* __restrict__ w, int* __restrict__ bcur,
                          uint2* __restrict__ buck, int E, int B) {
  __shared__ int h[BMAX], base[BMAX], cur[BMAX];
  const int tid = threadIdx.x;
  for (int i = tid; i < B; i += TPB) { h[i] = 0; cur[i] = 0; }
  __syncthreads();
  const int e0 = blockIdx.x * CHUNK;
  for (int k = tid; k < CHUNK; k += TPB) {
    int i = e0 + k;
    if (i < E) atomicAdd(&h[col[i] >> RBITS], 1);
  }
  __syncthreads();
  for (int i = tid; i < B; i += TPB)
    base[i] = h[i] ? atomicAdd(&bcur[i], h[i]) : 0;
  __syncthreads();
  for (int k = tid; k < CHUNK; k += TPB) {
    int i = e0 + k;
    if (i >= E) continue;
    int c = col[i];
    int b = c >> RBITS;
    int pos = base[b] + atomicAdd(&cur[b], 1);
    unsigned lc = (unsigned)(c & (RSZ - 1));
    buck[pos] = make_uint2((unsigned)row[i] | (lc << 19), __float_as_uint(w[i]));
  }
}

// per-bucket counting sort -> CSR; pk.y pre-multiplied by dinv[col] (local!)
__global__ __launch_bounds__(256) void k_bucket(const uint2* __restrict__ buck,
                                                const int* __restrict__ bbase,
                                                int* __restrict__ ptr, float* __restrict__ dinv,
                                                uint2* __restrict__ pk, int N, int E) {
  __shared__ int cnt[RSZ];
  __shared__ float wsum[RSZ];
  __shared__ int lofs[RSZ];
  __shared__ int red[256];
  const int bk = blockIdx.x, tid = threadIdx.x;
  const int n0 = bk << RBITS;
  const int nloc = min(RSZ, N - n0);
  for (int i = tid; i < RSZ; i += 256) { cnt[i] = 0; wsum[i] = 0.f; }
  __syncthreads();
  const int e0 = bbase[bk], e1 = bbase[bk + 1];
  for (int i = e0 + tid; i < e1; i += 256) {
    uint2 e = buck[i];
    int lc = e.x >> 19;
    atomicAdd(&cnt[lc], 1);
    atomicAdd(&wsum[lc], __uint_as_float(e.y));
  }
  __syncthreads();
  int a = cnt[tid * 4], b = cnt[tid * 4 + 1], c = cnt[tid * 4 + 2], d = cnt[tid * 4 + 3];
  int l1 = a, l2 = a + b, l3 = a + b + c, s = a + b + c + d;
  red[tid] = s;
  __syncthreads();
  for (int off = 1; off < 256; off <<= 1) {
    int u = (tid >= off) ? red[tid - off] : 0;
    __syncthreads();
    red[tid] += u;
    __syncthreads();
  }
  int tb = red[tid] - s;
  lofs[tid * 4] = tb; lofs[tid * 4 + 1] = tb + l1;
  lofs[tid * 4 + 2] = tb + l2; lofs[tid * 4 + 3] = tb + l3;
  __syncthreads();
  for (int i = tid; i < nloc; i += 256) {
    ptr[n0 + i] = e0 + lofs[i];
    dinv[n0 + i] = rsqrtf(1.0f + wsum[i]);  // deg >= 1 (self-loop)
  }
  for (int i = tid; i < RSZ; i += 256) cnt[i] = 0;
  __syncthreads();
  for (int i = e0 + tid; i < e1; i += 256) {
    uint2 e = buck[i];
    int lc = e.x >> 19;
    int pos = e0 + lofs[lc] + atomicAdd(&cnt[lc], 1);
    float wdc = __uint_as_float(e.y) * rsqrtf(1.0f + wsum[lc]);  // w * dinv[col]
    pk[pos] = make_uint2(e.x & 524287u, __float_as_uint(wdc));
  }
  if (bk == 0 && tid == 0) ptr[N] = E;
}

// finish norm edge-parallel: pk.y *= dinv[row]
__global__ void k_nrme(uint2* __restrict__ pk, const float* __restrict__ dinv, int E) {
  int e = blockIdx.x * blockDim.x + threadIdx.x;
  if (e < E) {
    uint2 v = pk[e];
    pk[e].y = __float_as_uint(__uint_as_float(v.y) * dinv[v.x]);
  }
}

// =================== layer 0 path: gather raw x, then (A.x)@W0 ===================
// A.(x@W0) == (A.x)@W0 -> gather on 16 B rows (N*8 bf16 = 6.4 MB working set,
// ~L2-resident) instead of 32-ch bf16 rows (25.6 MB).

__global__ void k_packx(const float* __restrict__ x, uint4* __restrict__ g, int N) {
  int n = blockIdx.x * 256 + threadIdx.x;
  if (n >= N) return;
  const float* p = x + (size_t)n * 7;
  unsigned b[8];
#pragma unroll
  for (int k = 0; k < 7; ++k) b[k] = f2bf(p[k]);
  b[7] = 0;
  uint4 o;
  o.x = b[0] | (b[1] << 16); o.y = b[2] | (b[3] << 16);
  o.z = b[4] | (b[5] << 16); o.w = b[6] | (b[7] << 16);
  g[n] = o;
}

// B1 = G1 @ W0 (G1 = A.x, 7 eff. channels) + fused BN stats (3-step shuffle
// butterfly over the 8 nodes sharing a wave's channel-group lanes — NOT the
// round-10 per-element LDS atomic storm).
__global__ __launch_bounds__(256) void k_transform0b(
    const uint4* __restrict__ g1, const float* __restrict__ W,
    float* __restrict__ gstats, uint2* __restrict__ t2, int N) {
  __shared__ float Ws[7 * 32];
  __shared__ float hs[32 * 9];
  __shared__ float sarr[64];
  const int tid = threadIdx.x;
  const int n0 = blockIdx.x * 32;
  if (tid < 224) Ws[tid] = W[tid];
  if (tid < 64) sarr[tid] = 0.f;
  if (tid < 32) {
    const int node = n0 + tid;
    uint4 v = make_uint4(0, 0, 0, 0);
    if (node < N) v = g1[node];
    float* h = &hs[tid * 9];
    h[0] = __uint_as_float(v.x << 16); h[1] = __uint_as_float(v.x & 0xffff0000u);
    h[2] = __uint_as_float(v.y << 16); h[3] = __uint_as_float(v.y & 0xffff0000u);
    h[4] = __uint_as_float(v.z << 16); h[5] = __uint_as_float(v.z & 0xffff0000u);
    h[6] = __uint_as_float(v.w << 16); h[7] = 0.f;
  }
  __syncthreads();
  const int j = tid >> 3, q = tid & 7, c0 = q * 4;
  const int node = n0 + j;
  float a0 = 0.f, a1 = 0.f, a2 = 0.f, a3 = 0.f;
#pragma unroll
  for (int k = 0; k < 7; ++k) {
    float v = hs[j * 9 + k];
    const float* w = &Ws[k * 32 + c0];
    a0 += v * w[0]; a1 += v * w[1]; a2 += v * w[2]; a3 += v * w[3];
  }
  if (node < N) {
    uint2 o;
    o.x = (unsigned)f2bf(a0) | ((unsigned)f2bf(a1) << 16);
    o.y = (unsigned)f2bf(a2) | ((unsigned)f2bf(a3) << 16);
    t2[(size_t)node * 8 + q] = o;
  }
  // stats: reduce over the 8 nodes in this wave's channel-group lanes
  float q0 = a0 * a0, q1 = a1 * a1, q2 = a2 * a2, q3 = a3 * a3;
#pragma unroll
  for (int m = 8; m < 64; m <<= 1) {
    a0 += __shfl_xor(a0, m, 64); a1 += __shfl_xor(a1, m, 64);
    a2 += __shfl_xor(a2, m, 64); a3 += __shfl_xor(a3, m, 64);
    q0 += __shfl_xor(q0, m, 64); q1 += __shfl_xor(q1, m, 64);
    q2 += __shfl_xor(q2, m, 64); q3 += __shfl_xor(q3, m, 64);
  }
  if ((tid & 63) < 8) {  // one lane per (wave, channel-group)
    atomicAdd(&sarr[c0 + 0], a0); atomicAdd(&sarr[c0 + 1], a1);
    atomicAdd(&sarr[c0 + 2], a2); atomicAdd(&sarr[c0 + 3], a3);
    atomicAdd(&sarr[32 + c0 + 0], q0); atomicAdd(&sarr[32 + c0 + 1], q1);
    atomicAdd(&sarr[32 + c0 + 2], q2); atomicAdd(&sarr[32 + c0 + 3], q3);
  }
  __syncthreads();
  if (tid < 64) unsafeAtomicAdd(&gstats[tid], sarr[tid]);
}

// =================== transforms layers 1-3 (unchanged r11 form) ===================

__global__ __launch_bounds__(256) void k_transform(
    const uint4* __restrict__ in4, const float* __restrict__ W,
    const float* __restrict__ gstats, const float* __restrict__ gamma,
    const float* __restrict__ beta, float invN, uint2* __restrict__ t2, int N) {
  __shared__ float Ws[1024];
  __shared__ float hs[32 * 33];
  __shared__ float ssb[64];
  const int tid = threadIdx.x;
  const int n0 = blockIdx.x * 32;
#pragma unroll
  for (int k = 0; k < 4; ++k) Ws[k * 256 + tid] = W[k * 256 + tid];
  if (tid < 32) {
    float m = gstats[tid] * invN;
    float v = gstats[32 + tid] * invN - m * m;
    float sc = gamma[tid] * rsqrtf(v + EPSV);
    ssb[tid] = sc;
    ssb[32 + tid] = beta[tid] - m * sc;
  }
  __syncthreads();
  if (tid < 128) {
    const int r = tid >> 2, q = tid & 3;
    const int node = n0 + r;
    uint4 v = make_uint4(0, 0, 0, 0);
    if (node < N) v = in4[(size_t)node * 4 + q];
    float* h = &hs[r * 33 + q * 8];
    const float* sc = &ssb[q * 8];
    const float* sh = &ssb[32 + q * 8];
    h[0] = fmaxf(__uint_as_float(v.x << 16) * sc[0] + sh[0], 0.f);
    h[1] = fmaxf(__uint_as_float(v.x & 0xffff0000u) * sc[1] + sh[1], 0.f);
    h[2] = fmaxf(__uint_as_float(v.y << 16) * sc[2] + sh[2], 0.f);
    h[3] = fmaxf(__uint_as_float(v.y & 0xffff0000u) * sc[3] + sh[3], 0.f);
    h[4] = fmaxf(__uint_as_float(v.z << 16) * sc[4] + sh[4], 0.f);
    h[5] = fmaxf(__uint_as_float(v.z & 0xffff0000u) * sc[5] + sh[5], 0.f);
    h[6] = fmaxf(__uint_as_float(v.w << 16) * sc[6] + sh[6], 0.f);
    h[7] = fmaxf(__uint_as_float(v.w & 0xffff0000u) * sc[7] + sh[7], 0.f);
  }
  __syncthreads();
  const int j = tid >> 3;
  const int c0 = (tid & 7) * 4;
  const int node = n0 + j;
  if (node < N) {
    float a0 = 0.f, a1 = 0.f, a2 = 0.f, a3 = 0.f;
#pragma unroll
    for (int k = 0; k < 32; ++k) {
      float v = hs[j * 33 + k];
      const float* w = &Ws[k * 32 + c0];
      a0 += v * w[0]; a1 += v * w[1]; a2 += v * w[2]; a3 += v * w[3];
    }
    uint2 o;
    o.x = (unsigned)f2bf(a0) | ((unsigned)f2bf(a1) << 16);
    o.y = (unsigned)f2bf(a2) | ((unsigned)f2bf(a3) << 16);
    t2[(size_t)node * 8 + (tid & 7)] = o;
  }
}

// =================== CSR gather: lane-per-node, templated row width ===================
// Q = uint4s per row (1 for layer-0 raw-x path, 4 for 32-ch). pk[p+1] is
// software-prefetched (pk has E+1 slots) so edge p's row loads overlap the
// next pk fetch.

__device__ __forceinline__ void fma8(float* acc, uint4 v, float wt) {
  acc[0] += wt * __uint_as_float(v.x << 16);
  acc[1] += wt * __uint_as_float(v.x & 0xffff0000u);
  acc[2] += wt * __uint_as_float(v.y << 16);
  acc[3] += wt * __uint_as_float(v.y & 0xffff0000u);
  acc[4] += wt * __uint_as_float(v.z << 16);
  acc[5] += wt * __uint_as_float(v.z & 0xffff0000u);
  acc[6] += wt * __uint_as_float(v.w << 16);
  acc[7] += wt * __uint_as_float(v.w & 0xffff0000u);
}

template <int Q>
__global__ __launch_bounds__(256, 4) void k_gather(
    const uint2* __restrict__ pk, const int* __restrict__ ptr,
    const float* __restrict__ dinv, const uint4* __restrict__ t4,
    uint4* __restrict__ out4, int N) {
  const int n = blockIdx.x * 256 + threadIdx.x;
  if (n >= N) return;
  const int p0 = ptr[n], p1 = ptr[n + 1];
  const float dvn = dinv[n];
  float acc[8 * Q];
#pragma unroll
  for (int k = 0; k < 8 * Q; ++k) acc[k] = 0.f;
  {
    const float wt = dvn * dvn;
    const size_t rb = (size_t)n * Q;
#pragma unroll
    for (int qq = 0; qq < Q; ++qq) fma8(acc + 8 * qq, t4[rb + qq], wt);
  }
  if (p0 < p1) {
    uint2 e = pk[p0];
    for (int p = p0; p < p1; ++p) {
      uint2 en = pk[p + 1];  // prefetch (pk allocated E+1)
      const float wt = __uint_as_float(e.y);
      const size_t rb = (size_t)e.x * Q;
#pragma unroll
      for (int qq = 0; qq < Q; ++qq) fma8(acc + 8 * qq, t4[rb + qq], wt);
      e = en;
    }
  }
  const size_t ob = (size_t)n * Q;
#pragma unroll
  for (int qq = 0; qq < Q; ++qq) {
    uint4 o;
    o.x = (unsigned)f2bf(acc[qq * 8 + 0]) | ((unsigned)f2bf(acc[qq * 8 + 1]) << 16);
    o.y = (unsigned)f2bf(acc[qq * 8 + 2]) | ((unsigned)f2bf(acc[qq * 8 + 3]) << 16);
    o.z = (unsigned)f2bf(acc[qq * 8 + 4]) | ((unsigned)f2bf(acc[qq * 8 + 5]) << 16);
    o.w = (unsigned)f2bf(acc[qq * 8 + 6]) | ((unsigned)f2bf(acc[qq * 8 + 7]) << 16);
    out4[ob + qq] = o;
  }
}

// =================== BN stats, vectorized (layers 1-2 outputs) ===================

__global__ void k_stats(const uint4* __restrict__ x4, float* __restrict__ gstats, int nquads) {
  __shared__ float ls[64];
  const int tid = threadIdx.x;
  if (tid < 64) ls[tid] = 0.f;
  __syncthreads();
  const int q = tid & 3;
  float s[8], sq[8];
#pragma unroll
  for (int k = 0; k < 8; ++k) { s[k] = 0.f; sq[k] = 0.f; }
  for (int idx = blockIdx.x * TPB + tid; idx < nquads; idx += gridDim.x * TPB) {
    uint4 v = x4[idx];
    float f0 = __uint_as_float(v.x << 16), f1 = __uint_as_float(v.x & 0xffff0000u);
    float f2 = __uint_as_float(v.y << 16), f3 = __uint_as_float(v.y & 0xffff0000u);
    float f4 = __uint_as_float(v.z << 16), f5 = __uint_as_float(v.z & 0xffff0000u);
    float f6 = __uint_as_float(v.w << 16), f7 = __uint_as_float(v.w & 0xffff0000u);
    s[0] += f0; sq[0] += f0 * f0;  s[1] += f1; sq[1] += f1 * f1;
    s[2] += f2; sq[2] += f2 * f2;  s[3] += f3; sq[3] += f3 * f3;
    s[4] += f4; sq[4] += f4 * f4;  s[5] += f5; sq[5] += f5 * f5;
    s[6] += f6; sq[6] += f6 * f6;  s[7] += f7; sq[7] += f7 * f7;
  }
#pragma unroll
  for (int k = 0; k < 8; ++k) {
    int c = q * 8 + k;
    atomicAdd(&ls[c], s[k]);
    atomicAdd(&ls[32 + c], sq[k]);
  }
  __syncthreads();
  if (tid < 64) unsafeAtomicAdd(&gstats[tid], ls[tid]);
}

// =================== global add pool (batch sorted, uint4 loads) ===================

__global__ __launch_bounds__(256) void k_pool(
    const uint4* __restrict__ h4, const int* __restrict__ batch,
    const float* __restrict__ b3, float* __restrict__ pool, int N) {
  __shared__ float red[64 * 33];
  const int g = blockIdx.x, tid = threadIdx.x;
  int lo = 0, hi = N;
  while (lo < hi) { int mid = (lo + hi) >> 1; if (batch[mid] < g) lo = mid + 1; else hi = mid; }
  const int start = lo;
  hi = N;
  while (lo < hi) { int mid = (lo + hi) >> 1; if (batch[mid] < g + 1) lo = mid + 1; else hi = mid; }
  const int end = lo;
  const int j = tid >> 2, q = tid & 3;
  float a[8];
#pragma unroll
  for (int k = 0; k < 8; ++k) a[k] = 0.f;
  for (int i = start + j; i < end; i += 64) {
    uint4 v = h4[(size_t)i * 4 + q];
    a[0] += __uint_as_float(v.x << 16); a[1] += __uint_as_float(v.x & 0xffff0000u);
    a[2] += __uint_as_float(v.y << 16); a[3] += __uint_as_float(v.y & 0xffff0000u);
    a[4] += __uint_as_float(v.z << 16); a[5] += __uint_as_float(v.z & 0xffff0000u);
    a[6] += __uint_as_float(v.w << 16); a[7] += __uint_as_float(v.w & 0xffff0000u);
  }
#pragma unroll
  for (int k = 0; k < 8; ++k) red[j * 33 + q * 8 + k] = a[k];
  __syncthreads();
  for (int off = 32; off >= 1; off >>= 1) {
    if (j < off) {
#pragma unroll
      for (int k = 0; k < 8; ++k)
        red[j * 33 + q * 8 + k] += red[(j + off) * 33 + q * 8 + k];
    }
    __syncthreads();
  }
  if (tid < 32) pool[g * 32 + tid] = red[tid] + (float)(end - start) * b3[tid];
}

// =================== MLP head ===================

__global__ void k_mlpz(const float* __restrict__ pool, const float* __restrict__ Wm0,
                       const float* __restrict__ bm0, float* __restrict__ z,
                       float* __restrict__ mstats) {
  __shared__ float Ws[32 * 32];
  __shared__ float ps[8 * 32];
  __shared__ float ls[TPB], lq[TPB];
  const int tid = threadIdx.x;
  const int g0 = blockIdx.x * 8;
  for (int k = tid; k < 1024; k += TPB) Ws[k] = Wm0[k];
  if (tid < 256) ps[tid] = pool[g0 * 32 + tid];
  __syncthreads();
  const int j = tid >> 5, c = tid & 31;
  float acc = bm0[c];
#pragma unroll
  for (int k = 0; k < 32; ++k) acc += ps[j * 32 + k] * Ws[k * 32 + c];
  z[(g0 + j) * 32 + c] = acc;
  ls[tid] = acc;
  lq[tid] = acc * acc;
  __syncthreads();
  for (int off = 128; off >= 32; off >>= 1) {
    if (tid < off) { ls[tid] += ls[tid + off]; lq[tid] += lq[tid + off]; }
    __syncthreads();
  }
  if (tid < 32) {
    unsafeAtomicAdd(&mstats[tid], ls[tid]);
    unsafeAtomicAdd(&mstats[32 + tid], lq[tid]);
  }
}

__global__ void k_mlpfin(const float* __restrict__ z, const float* __restrict__ mstats,
                         const float* __restrict__ bng, const float* __restrict__ bnb,
                         const float* __restrict__ Wm1, const float* __restrict__ bm1,
                         float* __restrict__ out) {
  __shared__ float sc[32], sh[32], w1[64];
  const int tid = threadIdx.x;
  if (tid < 32) {
    float m = mstats[tid] * (1.0f / 512.0f);
    float v = mstats[32 + tid] * (1.0f / 512.0f) - m * m;
    float s = bng[tid] * rsqrtf(v + EPSV);
    sc[tid] = s;
    sh[tid] = bnb[tid] - m * s;
  }
  if (tid < 64) w1[tid] = Wm1[tid];
  __syncthreads();
  const int g = tid >> 1, o = tid & 1;
  float acc = bm1[o];
#pragma unroll
  for (int c = 0; c < 32; ++c) {
    float hc = fmaxf(z[g * 32 + c] * sc[c] + sh[c], 0.f);
    acc += hc * w1[c * 2 + o];
  }
  out[tid] = acc;
}

// =================== launch ===================

extern "C" void kernel_launch(void* const* d_in, const int* in_sizes, int n_in,
                              void* d_out, int out_size, void* d_ws, size_t ws_size,
                              hipStream_t stream) {
  const float* x     = (const float*)d_in[0];
  const int*   ei    = (const int*)d_in[1];
  const float* ea    = (const float*)d_in[2];
  const int*   batch = (const int*)d_in[3];
  const float* W0    = (const float*)d_in[4];
  const float* W1    = (const float*)d_in[6];
  const float* W2    = (const float*)d_in[8];
  const float* W3    = (const float*)d_in[10];
  const float* b3    = (const float*)d_in[11];
  const float* bng   = (const float*)d_in[12];  // [3,32]
  const float* bnb   = (const float*)d_in[13];
  const float* Wm0   = (const float*)d_in[14];
  const float* bm0   = (const float*)d_in[15];
  const float* bnmg  = (const float*)d_in[16];
  const float* bnmb  = (const float*)d_in[17];
  const float* Wm1   = (const float*)d_in[18];
  const float* bm1   = (const float*)d_in[19];
  float* out = (float*)d_out;

  const int N = in_sizes[3];
  const int E = in_sizes[2];
  const int* row = ei;
  const int* col = ei + E;
  const int B = (N + RSZ - 1) >> RBITS;

  char* wsb = (char*)d_ws;
  auto alloc = [&](size_t bytes) { char* p = wsb; wsb += (bytes + 255) & ~size_t(255); return p; };
  int*   bcnt  = (int*)alloc((size_t)(BMAX + 1) * 4);
  int*   bbase = (int*)alloc((size_t)(BMAX + 1) * 4);
  int*   bcur  = (int*)alloc((size_t)BMAX * 4);
  int*   ptr   = (int*)alloc((size_t)(N + 1) * 4);
  uint2* buck  = (uint2*)alloc((size_t)E * 8);
  uint2* pk    = (uint2*)alloc((size_t)(E + 1) * 8);  // +1: prefetch slot
  float* dinv  = (float*)alloc((size_t)N * 4);
  uint4* G0    = (uint4*)alloc((size_t)N * 16);       // packed x (8 bf16)
  uint4* G1    = (uint4*)alloc((size_t)N * 16);       // A.x
  unsigned short* B0 = (unsigned short*)alloc((size_t)N * 32 * 2);  // bf16
  unsigned short* B1 = (unsigned short*)alloc((size_t)N * 32 * 2);  // bf16
  float* stats = (float*)alloc(4 * 64 * 4);
  float* pool  = (float*)alloc(512 * 32 * 4);
  float* zbuf  = (float*)alloc(512 * 32 * 4);

  hipMemsetAsync(bcnt, 0, (size_t)(BMAX + 1) * 4, stream);
  hipMemsetAsync(stats, 0, 4 * 64 * 4, stream);

  const int nb_c = (E + CHUNK - 1) / CHUNK;
  const int nb_e = (E + 255) / 256;
  const int nb_t = (N + 31) / 32;
  const int nb_g = (N + 255) / 256;
  const int nquads = N * 4;
  const float invN = 1.0f / (float)N;
  float* mstats = stats + 192;

  // ---- CSR build (bucketed) ----
  k_bcnt<<<nb_c, TPB, 0, stream>>>(col, bcnt, E, B);
  k_bscan<<<1, BMAX, 0, stream>>>(bcnt, bbase, bcur, B, E);
  k_binfill<<<nb_c, TPB, 0, stream>>>(row, col, ea, bcur, buck, E, B);
  k_bucket<<<B, 256, 0, stream>>>(buck, bbase, ptr, dinv, pk, N, E);
  k_nrme<<<nb_e, 256, 0, stream>>>(pk, dinv, E);

  // ---- layer 0: gather raw x, then (A.x)@W0 with fused stats ----
  k_packx<<<nb_g, 256, 0, stream>>>(x, G0, N);
  k_gather<1><<<nb_g, 256, 0, stream>>>(pk, ptr, dinv, G0, G1, N);
  k_transform0b<<<nb_t, 256, 0, stream>>>(G1, W0, stats, (uint2*)B1, N);

  // ---- layer 1 ----
  k_transform<<<nb_t, 256, 0, stream>>>((const uint4*)B1, W1, stats, bng, bnb, invN,
                                        (uint2*)B0, N);
  k_gather<4><<<nb_g, 256, 0, stream>>>(pk, ptr, dinv, (const uint4*)B0, (uint4*)B1, N);
  k_stats<<<1024, TPB, 0, stream>>>((const uint4*)B1, stats + 64, nquads);

  // ---- layer 2 ----
  k_transform<<<nb_t, 256, 0, stream>>>((const uint4*)B1, W2, stats + 64, bng + 32, bnb + 32,
                                        invN, (uint2*)B0, N);
  k_gather<4><<<nb_g, 256, 0, stream>>>(pk, ptr, dinv, (const uint4*)B0, (uint4*)B1, N);
  k_stats<<<1024, TPB, 0, stream>>>((const uint4*)B1, stats + 128, nquads);

  // ---- layer 3 (no BN on output) ----
  k_transform<<<nb_t, 256, 0, stream>>>((const uint4*)B1, W3, stats + 128, bng + 64, bnb + 64,
                                        invN, (uint2*)B0, N);
  k_gather<4><<<nb_g, 256, 0, stream>>>(pk, ptr, dinv, (const uint4*)B0, (uint4*)B1, N);

  // ---- pool + MLP head ----
  k_pool<<<512, 256, 0, stream>>>((const uint4*)B1, batch, b3, pool, N);
  k_mlpz<<<64, TPB, 0, stream>>>(pool, Wm0, bm0, zbuf, mstats);
  k_mlpfin<<<1, 1024, 0, stream>>>(zbuf, mstats, bnmg, bnmb, Wm1, bm1, out);
}

// Round 13
// 713.928 us; speedup vs baseline: 1.3786x; 1.3786x over previous
//
#include <hip/hip_runtime.h>

#define TPB 256
#define RBITS 10               // bucket = node >> 10 (1024 nodes/bucket)
#define RSZ   1024
#define BMAX  512              // max buckets supported (N <= 512K)
#define CHUNK 4096             // edges per block in bucket passes
constexpr float EPSV = 1e-5f;

__device__ __forceinline__ float bf2f(unsigned short u) {
  return __uint_as_float((unsigned)u << 16);
}
__device__ __forceinline__ unsigned short f2bf(float f) {
  unsigned u = __float_as_uint(f);
  return (unsigned short)((u + 0x7fffu + ((u >> 16) & 1u)) >> 16);  // RNE
}

// =================== bucket-sorted CSR build ===================

__global__ void k_bcnt(const int* __restrict__ col, int* __restrict__ bcnt, int E, int B) {
  __shared__ int h[BMAX];
  const int tid = threadIdx.x;
  for (int i = tid; i < B; i += TPB) h[i] = 0;
  __syncthreads();
  const int e0 = blockIdx.x * CHUNK;
  for (int k = tid; k < CHUNK; k += TPB) {
    int i = e0 + k;
    if (i < E) atomicAdd(&h[col[i] >> RBITS], 1);
  }
  __syncthreads();
  for (int i = tid; i < B; i += TPB)
    if (h[i]) atomicAdd(&bcnt[i], h[i]);
}

__global__ void k_bscan(const int* __restrict__ bcnt, int* __restrict__ bbase,
                        int* __restrict__ bcur, int B, int E) {
  __shared__ int red[BMAX];
  const int tid = threadIdx.x;  // 512 threads
  int v = (tid < B) ? bcnt[tid] : 0;
  red[tid] = v;
  __syncthreads();
  for (int off = 1; off < BMAX; off <<= 1) {
    int u = (tid >= off) ? red[tid - off] : 0;
    __syncthreads();
    red[tid] += u;
    __syncthreads();
  }
  int excl = red[tid] - v;
  if (tid < B) { bbase[tid] = excl; bcur[tid] = excl; }
  if (tid == 0) bbase[B] = E;
}

__global__ void k_binfill(const int* __restrict__ row, const int* __restrict__ col,
                          const float* __restrict__ w, int* __restrict__ bcur,
                          uint2* __restrict__ buck, int E, int B) {
  __shared__ int h[BMAX], base[BMAX], cur[BMAX];
  const int tid = threadIdx.x;
  for (int i = tid; i < B; i += TPB) { h[i] = 0; cur[i] = 0; }
  __syncthreads();
  const int e0 = blockIdx.x * CHUNK;
  for (int k = tid; k < CHUNK; k += TPB) {
    int i = e0 + k;
    if (i < E) atomicAdd(&h[col[i] >> RBITS], 1);
  }
  __syncthreads();
  for (int i = tid; i < B; i += TPB)
    base[i] = h[i] ? atomicAdd(&bcur[i], h[i]) : 0;
  __syncthreads();
  for (int k = tid; k < CHUNK; k += TPB) {
    int i = e0 + k;
    if (i >= E) continue;
    int c = col[i];
    int b = c >> RBITS;
    int pos = base[b] + atomicAdd(&cur[b], 1);
    unsigned lc = (unsigned)(c & (RSZ - 1));
    buck[pos] = make_uint2((unsigned)row[i] | (lc << 19), __float_as_uint(w[i]));
  }
}

// per-bucket counting sort -> CSR; pk.y pre-multiplied by dinv[col] (local!)
__global__ __launch_bounds__(256) void k_bucket(const uint2* __restrict__ buck,
                                                const int* __restrict__ bbase,
                                                int* __restrict__ ptr, float* __restrict__ dinv,
                                                uint2* __restrict__ pk, int N, int E) {
  __shared__ int cnt[RSZ];
  __shared__ float wsum[RSZ];
  __shared__ int lofs[RSZ];
  __shared__ int red[256];
  const int bk = blockIdx.x, tid = threadIdx.x;
  const int n0 = bk << RBITS;
  const int nloc = min(RSZ, N - n0);
  for (int i = tid; i < RSZ; i += 256) { cnt[i] = 0; wsum[i] = 0.f; }
  __syncthreads();
  const int e0 = bbase[bk], e1 = bbase[bk + 1];
  for (int i = e0 + tid; i < e1; i += 256) {
    uint2 e = buck[i];
    int lc = e.x >> 19;
    atomicAdd(&cnt[lc], 1);
    atomicAdd(&wsum[lc], __uint_as_float(e.y));
  }
  __syncthreads();
  int a = cnt[tid * 4], b = cnt[tid * 4 + 1], c = cnt[tid * 4 + 2], d = cnt[tid * 4 + 3];
  int l1 = a, l2 = a + b, l3 = a + b + c, s = a + b + c + d;
  red[tid] = s;
  __syncthreads();
  for (int off = 1; off < 256; off <<= 1) {
    int u = (tid >= off) ? red[tid - off] : 0;
    __syncthreads();
    red[tid] += u;
    __syncthreads();
  }
  int tb = red[tid] - s;
  lofs[tid * 4] = tb; lofs[tid * 4 + 1] = tb + l1;
  lofs[tid * 4 + 2] = tb + l2; lofs[tid * 4 + 3] = tb + l3;
  __syncthreads();
  for (int i = tid; i < nloc; i += 256) {
    ptr[n0 + i] = e0 + lofs[i];
    dinv[n0 + i] = rsqrtf(1.0f + wsum[i]);  // deg >= 1 (self-loop)
  }
  for (int i = tid; i < RSZ; i += 256) cnt[i] = 0;
  __syncthreads();
  for (int i = e0 + tid; i < e1; i += 256) {
    uint2 e = buck[i];
    int lc = e.x >> 19;
    int pos = e0 + lofs[lc] + atomicAdd(&cnt[lc], 1);
    float wdc = __uint_as_float(e.y) * rsqrtf(1.0f + wsum[lc]);  // w * dinv[col]
    pk[pos] = make_uint2(e.x & 524287u, __float_as_uint(wdc));
  }
  if (bk == 0 && tid == 0) ptr[N] = E;
}

// finish norm edge-parallel: pk.y *= dinv[row]
__global__ void k_nrme(uint2* __restrict__ pk, const float* __restrict__ dinv, int E) {
  int e = blockIdx.x * blockDim.x + threadIdx.x;
  if (e < E) {
    uint2 v = pk[e];
    pk[e].y = __float_as_uint(__uint_as_float(v.y) * dinv[v.x]);
  }
}

// =================== layer 0 path: gather raw x, then (A.x)@W0 ===================
// A.(x@W0) == (A.x)@W0 -> gather on 16 B rows (6.4 MB working set, ~L2-hot).

__global__ void k_packx(const float* __restrict__ x, uint4* __restrict__ g, int N) {
  int n = blockIdx.x * 256 + threadIdx.x;
  if (n >= N) return;
  const float* p = x + (size_t)n * 7;
  unsigned b[8];
#pragma unroll
  for (int k = 0; k < 7; ++k) b[k] = f2bf(p[k]);
  b[7] = 0;
  uint4 o;
  o.x = b[0] | (b[1] << 16); o.y = b[2] | (b[3] << 16);
  o.z = b[4] | (b[5] << 16); o.w = b[6] | (b[7] << 16);
  g[n] = o;
}

// B1 = G1 @ W0. NO fused stats: a 12500-block kernel flushing 64 global
// atomics/block = 800K contended atomics on 2 cache lines (r12: 306 us,
// VALUBusy 2.6%). The 1024-block k_stats pass costs ~8 us instead.
__global__ __launch_bounds__(256) void k_transform0b(
    const uint4* __restrict__ g1, const float* __restrict__ W,
    uint2* __restrict__ t2, int N) {
  __shared__ float Ws[7 * 32];
  __shared__ float hs[32 * 9];
  const int tid = threadIdx.x;
  const int n0 = blockIdx.x * 32;
  if (tid < 224) Ws[tid] = W[tid];
  if (tid < 32) {
    const int node = n0 + tid;
    uint4 v = make_uint4(0, 0, 0, 0);
    if (node < N) v = g1[node];
    float* h = &hs[tid * 9];
    h[0] = __uint_as_float(v.x << 16); h[1] = __uint_as_float(v.x & 0xffff0000u);
    h[2] = __uint_as_float(v.y << 16); h[3] = __uint_as_float(v.y & 0xffff0000u);
    h[4] = __uint_as_float(v.z << 16); h[5] = __uint_as_float(v.z & 0xffff0000u);
    h[6] = __uint_as_float(v.w << 16); h[7] = 0.f;
  }
  __syncthreads();
  const int j = tid >> 3, q = tid & 7, c0 = q * 4;
  const int node = n0 + j;
  if (node < N) {
    float a0 = 0.f, a1 = 0.f, a2 = 0.f, a3 = 0.f;
#pragma unroll
    for (int k = 0; k < 7; ++k) {
      float v = hs[j * 9 + k];
      const float* w = &Ws[k * 32 + c0];
      a0 += v * w[0]; a1 += v * w[1]; a2 += v * w[2]; a3 += v * w[3];
    }
    uint2 o;
    o.x = (unsigned)f2bf(a0) | ((unsigned)f2bf(a1) << 16);
    o.y = (unsigned)f2bf(a2) | ((unsigned)f2bf(a3) << 16);
    t2[(size_t)node * 8 + q] = o;
  }
}

// =================== transforms layers 1-3 ===================

__global__ __launch_bounds__(256) void k_transform(
    const uint4* __restrict__ in4, const float* __restrict__ W,
    const float* __restrict__ gstats, const float* __restrict__ gamma,
    const float* __restrict__ beta, float invN, uint2* __restrict__ t2, int N) {
  __shared__ float Ws[1024];
  __shared__ float hs[32 * 33];
  __shared__ float ssb[64];
  const int tid = threadIdx.x;
  const int n0 = blockIdx.x * 32;
#pragma unroll
  for (int k = 0; k < 4; ++k) Ws[k * 256 + tid] = W[k * 256 + tid];
  if (tid < 32) {
    float m = gstats[tid] * invN;
    float v = gstats[32 + tid] * invN - m * m;
    float sc = gamma[tid] * rsqrtf(v + EPSV);
    ssb[tid] = sc;
    ssb[32 + tid] = beta[tid] - m * sc;
  }
  __syncthreads();
  if (tid < 128) {
    const int r = tid >> 2, q = tid & 3;
    const int node = n0 + r;
    uint4 v = make_uint4(0, 0, 0, 0);
    if (node < N) v = in4[(size_t)node * 4 + q];
    float* h = &hs[r * 33 + q * 8];
    const float* sc = &ssb[q * 8];
    const float* sh = &ssb[32 + q * 8];
    h[0] = fmaxf(__uint_as_float(v.x << 16) * sc[0] + sh[0], 0.f);
    h[1] = fmaxf(__uint_as_float(v.x & 0xffff0000u) * sc[1] + sh[1], 0.f);
    h[2] = fmaxf(__uint_as_float(v.y << 16) * sc[2] + sh[2], 0.f);
    h[3] = fmaxf(__uint_as_float(v.y & 0xffff0000u) * sc[3] + sh[3], 0.f);
    h[4] = fmaxf(__uint_as_float(v.z << 16) * sc[4] + sh[4], 0.f);
    h[5] = fmaxf(__uint_as_float(v.z & 0xffff0000u) * sc[5] + sh[5], 0.f);
    h[6] = fmaxf(__uint_as_float(v.w << 16) * sc[6] + sh[6], 0.f);
    h[7] = fmaxf(__uint_as_float(v.w & 0xffff0000u) * sc[7] + sh[7], 0.f);
  }
  __syncthreads();
  const int j = tid >> 3;
  const int c0 = (tid & 7) * 4;
  const int node = n0 + j;
  if (node < N) {
    float a0 = 0.f, a1 = 0.f, a2 = 0.f, a3 = 0.f;
#pragma unroll
    for (int k = 0; k < 32; ++k) {
      float v = hs[j * 33 + k];
      const float* w = &Ws[k * 32 + c0];
      a0 += v * w[0]; a1 += v * w[1]; a2 += v * w[2]; a3 += v * w[3];
    }
    uint2 o;
    o.x = (unsigned)f2bf(a0) | ((unsigned)f2bf(a1) << 16);
    o.y = (unsigned)f2bf(a2) | ((unsigned)f2bf(a3) << 16);
    t2[(size_t)node * 8 + (tid & 7)] = o;
  }
}

// =================== CSR gather: lane-per-node, templated row width ===================

__device__ __forceinline__ void fma8(float* acc, uint4 v, float wt) {
  acc[0] += wt * __uint_as_float(v.x << 16);
  acc[1] += wt * __uint_as_float(v.x & 0xffff0000u);
  acc[2] += wt * __uint_as_float(v.y << 16);
  acc[3] += wt * __uint_as_float(v.y & 0xffff0000u);
  acc[4] += wt * __uint_as_float(v.z << 16);
  acc[5] += wt * __uint_as_float(v.z & 0xffff0000u);
  acc[6] += wt * __uint_as_float(v.w << 16);
  acc[7] += wt * __uint_as_float(v.w & 0xffff0000u);
}

template <int Q>
__global__ __launch_bounds__(256, 4) void k_gather(
    const uint2* __restrict__ pk, const int* __restrict__ ptr,
    const float* __restrict__ dinv, const uint4* __restrict__ t4,
    uint4* __restrict__ out4, int N) {
  const int n = blockIdx.x * 256 + threadIdx.x;
  if (n >= N) return;
  const int p0 = ptr[n], p1 = ptr[n + 1];
  const float dvn = dinv[n];
  float acc[8 * Q];
#pragma unroll
  for (int k = 0; k < 8 * Q; ++k) acc[k] = 0.f;
  {
    const float wt = dvn * dvn;
    const size_t rb = (size_t)n * Q;
#pragma unroll
    for (int qq = 0; qq < Q; ++qq) fma8(acc + 8 * qq, t4[rb + qq], wt);
  }
  if (p0 < p1) {
    uint2 e = pk[p0];
    for (int p = p0; p < p1; ++p) {
      uint2 en = pk[p + 1];  // prefetch (pk allocated E+1)
      const float wt = __uint_as_float(e.y);
      const size_t rb = (size_t)e.x * Q;
#pragma unroll
      for (int qq = 0; qq < Q; ++qq) fma8(acc + 8 * qq, t4[rb + qq], wt);
      e = en;
    }
  }
  const size_t ob = (size_t)n * Q;
#pragma unroll
  for (int qq = 0; qq < Q; ++qq) {
    uint4 o;
    o.x = (unsigned)f2bf(acc[qq * 8 + 0]) | ((unsigned)f2bf(acc[qq * 8 + 1]) << 16);
    o.y = (unsigned)f2bf(acc[qq * 8 + 2]) | ((unsigned)f2bf(acc[qq * 8 + 3]) << 16);
    o.z = (unsigned)f2bf(acc[qq * 8 + 4]) | ((unsigned)f2bf(acc[qq * 8 + 5]) << 16);
    o.w = (unsigned)f2bf(acc[qq * 8 + 6]) | ((unsigned)f2bf(acc[qq * 8 + 7]) << 16);
    out4[ob + qq] = o;
  }
}

// =================== BN stats, vectorized (uint4 = 8 bf16 per load) ===================

__global__ void k_stats(const uint4* __restrict__ x4, float* __restrict__ gstats, int nquads) {
  __shared__ float ls[64];
  const int tid = threadIdx.x;
  if (tid < 64) ls[tid] = 0.f;
  __syncthreads();
  const int q = tid & 3;
  float s[8], sq[8];
#pragma unroll
  for (int k = 0; k < 8; ++k) { s[k] = 0.f; sq[k] = 0.f; }
  for (int idx = blockIdx.x * TPB + tid; idx < nquads; idx += gridDim.x * TPB) {
    uint4 v = x4[idx];
    float f0 = __uint_as_float(v.x << 16), f1 = __uint_as_float(v.x & 0xffff0000u);
    float f2 = __uint_as_float(v.y << 16), f3 = __uint_as_float(v.y & 0xffff0000u);
    float f4 = __uint_as_float(v.z << 16), f5 = __uint_as_float(v.z & 0xffff0000u);
    float f6 = __uint_as_float(v.w << 16), f7 = __uint_as_float(v.w & 0xffff0000u);
    s[0] += f0; sq[0] += f0 * f0;  s[1] += f1; sq[1] += f1 * f1;
    s[2] += f2; sq[2] += f2 * f2;  s[3] += f3; sq[3] += f3 * f3;
    s[4] += f4; sq[4] += f4 * f4;  s[5] += f5; sq[5] += f5 * f5;
    s[6] += f6; sq[6] += f6 * f6;  s[7] += f7; sq[7] += f7 * f7;
  }
#pragma unroll
  for (int k = 0; k < 8; ++k) {
    int c = q * 8 + k;
    atomicAdd(&ls[c], s[k]);
    atomicAdd(&ls[32 + c], sq[k]);
  }
  __syncthreads();
  if (tid < 64) unsafeAtomicAdd(&gstats[tid], ls[tid]);
}

// =================== global add pool (batch sorted, uint4 loads) ===================

__global__ __launch_bounds__(256) void k_pool(
    const uint4* __restrict__ h4, const int* __restrict__ batch,
    const float* __restrict__ b3, float* __restrict__ pool, int N) {
  __shared__ float red[64 * 33];
  const int g = blockIdx.x, tid = threadIdx.x;
  int lo = 0, hi = N;
  while (lo < hi) { int mid = (lo + hi) >> 1; if (batch[mid] < g) lo = mid + 1; else hi = mid; }
  const int start = lo;
  hi = N;
  while (lo < hi) { int mid = (lo + hi) >> 1; if (batch[mid] < g + 1) lo = mid + 1; else hi = mid; }
  const int end = lo;
  const int j = tid >> 2, q = tid & 3;
  float a[8];
#pragma unroll
  for (int k = 0; k < 8; ++k) a[k] = 0.f;
  for (int i = start + j; i < end; i += 64) {
    uint4 v = h4[(size_t)i * 4 + q];
    a[0] += __uint_as_float(v.x << 16); a[1] += __uint_as_float(v.x & 0xffff0000u);
    a[2] += __uint_as_float(v.y << 16); a[3] += __uint_as_float(v.y & 0xffff0000u);
    a[4] += __uint_as_float(v.z << 16); a[5] += __uint_as_float(v.z & 0xffff0000u);
    a[6] += __uint_as_float(v.w << 16); a[7] += __uint_as_float(v.w & 0xffff0000u);
  }
#pragma unroll
  for (int k = 0; k < 8; ++k) red[j * 33 + q * 8 + k] = a[k];
  __syncthreads();
  for (int off = 32; off >= 1; off >>= 1) {
    if (j < off) {
#pragma unroll
      for (int k = 0; k < 8; ++k)
        red[j * 33 + q * 8 + k] += red[(j + off) * 33 + q * 8 + k];
    }
    __syncthreads();
  }
  if (tid < 32) pool[g * 32 + tid] = red[tid] + (float)(end - start) * b3[tid];
}

// =================== MLP head ===================

__global__ void k_mlpz(const float* __restrict__ pool, const float* __restrict__ Wm0,
                       const float* __restrict__ bm0, float* __restrict__ z,
                       float* __restrict__ mstats) {
  __shared__ float Ws[32 * 32];
  __shared__ float ps[8 * 32];
  __shared__ float ls[TPB], lq[TPB];
  const int tid = threadIdx.x;
  const int g0 = blockIdx.x * 8;
  for (int k = tid; k < 1024; k += TPB) Ws[k] = Wm0[k];
  if (tid < 256) ps[tid] = pool[g0 * 32 + tid];
  __syncthreads();
  const int j = tid >> 5, c = tid & 31;
  float acc = bm0[c];
#pragma unroll
  for (int k = 0; k < 32; ++k) acc += ps[j * 32 + k] * Ws[k * 32 + c];
  z[(g0 + j) * 32 + c] = acc;
  ls[tid] = acc;
  lq[tid] = acc * acc;
  __syncthreads();
  for (int off = 128; off >= 32; off >>= 1) {
    if (tid < off) { ls[tid] += ls[tid + off]; lq[tid] += lq[tid + off]; }
    __syncthreads();
  }
  if (tid < 32) {
    unsafeAtomicAdd(&mstats[tid], ls[tid]);
    unsafeAtomicAdd(&mstats[32 + tid], lq[tid]);
  }
}

__global__ void k_mlpfin(const float* __restrict__ z, const float* __restrict__ mstats,
                         const float* __restrict__ bng, const float* __restrict__ bnb,
                         const float* __restrict__ Wm1, const float* __restrict__ bm1,
                         float* __restrict__ out) {
  __shared__ float sc[32], sh[32], w1[64];
  const int tid = threadIdx.x;
  if (tid < 32) {
    float m = mstats[tid] * (1.0f / 512.0f);
    float v = mstats[32 + tid] * (1.0f / 512.0f) - m * m;
    float s = bng[tid] * rsqrtf(v + EPSV);
    sc[tid] = s;
    sh[tid] = bnb[tid] - m * s;
  }
  if (tid < 64) w1[tid] = Wm1[tid];
  __syncthreads();
  const int g = tid >> 1, o = tid & 1;
  float acc = bm1[o];
#pragma unroll
  for (int c = 0; c < 32; ++c) {
    float hc = fmaxf(z[g * 32 + c] * sc[c] + sh[c], 0.f);
    acc += hc * w1[c * 2 + o];
  }
  out[tid] = acc;
}

// =================== launch ===================

extern "C" void kernel_launch(void* const* d_in, const int* in_sizes, int n_in,
                              void* d_out, int out_size, void* d_ws, size_t ws_size,
                              hipStream_t stream) {
  const float* x     = (const float*)d_in[0];
  const int*   ei    = (const int*)d_in[1];
  const float* ea    = (const float*)d_in[2];
  const int*   batch = (const int*)d_in[3];
  const float* W0    = (const float*)d_in[4];
  const float* W1    = (const float*)d_in[6];
  const float* W2    = (const float*)d_in[8];
  const float* W3    = (const float*)d_in[10];
  const float* b3    = (const float*)d_in[11];
  const float* bng   = (const float*)d_in[12];  // [3,32]
  const float* bnb   = (const float*)d_in[13];
  const float* Wm0   = (const float*)d_in[14];
  const float* bm0   = (const float*)d_in[15];
  const float* bnmg  = (const float*)d_in[16];
  const float* bnmb  = (const float*)d_in[17];
  const float* Wm1   = (const float*)d_in[18];
  const float* bm1   = (const float*)d_in[19];
  float* out = (float*)d_out;

  const int N = in_sizes[3];
  const int E = in_sizes[2];
  const int* row = ei;
  const int* col = ei + E;
  const int B = (N + RSZ - 1) >> RBITS;

  char* wsb = (char*)d_ws;
  auto alloc = [&](size_t bytes) { char* p = wsb; wsb += (bytes + 255) & ~size_t(255); return p; };
  int*   bcnt  = (int*)alloc((size_t)(BMAX + 1) * 4);
  int*   bbase = (int*)alloc((size_t)(BMAX + 1) * 4);
  int*   bcur  = (int*)alloc((size_t)BMAX * 4);
  int*   ptr   = (int*)alloc((size_t)(N + 1) * 4);
  uint2* buck  = (uint2*)alloc((size_t)E * 8);
  uint2* pk    = (uint2*)alloc((size_t)(E + 1) * 8);  // +1: prefetch slot
  float* dinv  = (float*)alloc((size_t)N * 4);
  uint4* G0    = (uint4*)alloc((size_t)N * 16);       // packed x (8 bf16)
  uint4* G1    = (uint4*)alloc((size_t)N * 16);       // A.x
  unsigned short* B0 = (unsigned short*)alloc((size_t)N * 32 * 2);  // bf16
  unsigned short* B1 = (unsigned short*)alloc((size_t)N * 32 * 2);  // bf16
  float* stats = (float*)alloc(4 * 64 * 4);
  float* pool  = (float*)alloc(512 * 32 * 4);
  float* zbuf  = (float*)alloc(512 * 32 * 4);

  hipMemsetAsync(bcnt, 0, (size_t)(BMAX + 1) * 4, stream);
  hipMemsetAsync(stats, 0, 4 * 64 * 4, stream);

  const int nb_c = (E + CHUNK - 1) / CHUNK;
  const int nb_e = (E + 255) / 256;
  const int nb_t = (N + 31) / 32;
  const int nb_g = (N + 255) / 256;
  const int nquads = N * 4;
  const float invN = 1.0f / (float)N;
  float* mstats = stats + 192;

  // ---- CSR build (bucketed) ----
  k_bcnt<<<nb_c, TPB, 0, stream>>>(col, bcnt, E, B);
  k_bscan<<<1, BMAX, 0, stream>>>(bcnt, bbase, bcur, B, E);
  k_binfill<<<nb_c, TPB, 0, stream>>>(row, col, ea, bcur, buck, E, B);
  k_bucket<<<B, 256, 0, stream>>>(buck, bbase, ptr, dinv, pk, N, E);
  k_nrme<<<nb_e, 256, 0, stream>>>(pk, dinv, E);

  // ---- layer 0: gather raw x, then (A.x)@W0; stats in separate 1024-blk pass ----
  k_packx<<<nb_g, 256, 0, stream>>>(x, G0, N);
  k_gather<1><<<nb_g, 256, 0, stream>>>(pk, ptr, dinv, G0, G1, N);
  k_transform0b<<<nb_t, 256, 0, stream>>>(G1, W0, (uint2*)B1, N);
  k_stats<<<1024, TPB, 0, stream>>>((const uint4*)B1, stats, nquads);

  // ---- layer 1 ----
  k_transform<<<nb_t, 256, 0, stream>>>((const uint4*)B1, W1, stats, bng, bnb, invN,
                                        (uint2*)B0, N);
  k_gather<4><<<nb_g, 256, 0, stream>>>(pk, ptr, dinv, (const uint4*)B0, (uint4*)B1, N);
  k_stats<<<1024, TPB, 0, stream>>>((const uint4*)B1, stats + 64, nquads);

  // ---- layer 2 ----
  k_transform<<<nb_t, 256, 0, stream>>>((const uint4*)B1, W2, stats + 64, bng + 32, bnb + 32,
                                        invN, (uint2*)B0, N);
  k_gather<4><<<nb_g, 256, 0, stream>>>(pk, ptr, dinv, (const uint4*)B0, (uint4*)B1, N);
  k_stats<<<1024, TPB, 0, stream>>>((const uint4*)B1, stats + 128, nquads);

  // ---- layer 3 (no BN on output) ----
  k_transform<<<nb_t, 256, 0, stream>>>((const uint4*)B1, W3, stats + 128, bng + 64, bnb + 64,
                                        invN, (uint2*)B0, N);
  k_gather<4><<<nb_g, 256, 0, stream>>>(pk, ptr, dinv, (const uint4*)B0, (uint4*)B1, N);

  // ---- pool + MLP head ----
  k_pool<<<512, 256, 0, stream>>>((const uint4*)B1, batch, b3, pool, N);
  k_mlpz<<<64, TPB, 0, stream>>>(pool, Wm0, bm0, zbuf, mstats);
  k_mlpfin<<<1, 1024, 0, stream>>>(zbuf, mstats, bnmg, bnmb, Wm1, bm1, out);
}